// Round 18
// baseline (121.648 us; speedup 1.0000x reference)
//
#include <hip/hip_runtime.h>
#include <cmath>

// B=8, Cin=16, H=W=128, Cout=64, E=16, K=2
typedef __attribute__((ext_vector_type(8))) short bf16x8;   // MFMA A/B frag
typedef __attribute__((ext_vector_type(4))) float f32x4;    // MFMA C/D frag

static __device__ __forceinline__ unsigned int f2bf(float f) {
    union { float f; unsigned int u; } v; v.f = f;
    unsigned int r = v.u + 0x7FFFu + ((v.u >> 16) & 1u);   // round-to-nearest-even
    return r >> 16;
}

// Pack 16 floats -> 16 bf16 -> two 16B LDS stores
static __device__ __forceinline__ void pack16(unsigned short* d, const float* v) {
    uint4 a, b2;
    a.x  = f2bf(v[0])  | (f2bf(v[1])  << 16);
    a.y  = f2bf(v[2])  | (f2bf(v[3])  << 16);
    a.z  = f2bf(v[4])  | (f2bf(v[5])  << 16);
    a.w  = f2bf(v[6])  | (f2bf(v[7])  << 16);
    b2.x = f2bf(v[8])  | (f2bf(v[9])  << 16);
    b2.y = f2bf(v[10]) | (f2bf(v[11]) << 16);
    b2.z = f2bf(v[12]) | (f2bf(v[13]) << 16);
    b2.w = f2bf(v[14]) | (f2bf(v[15]) << 16);
    *(uint4*)d       = a;
    *(uint4*)(d + 8) = b2;
}

// ---- prep: ew [16][64][144] fp32 + eb -> wb chunks [e][ks][nf][quad][lq] x 8 bf16 ----
// K-PERMUTED layout: k' = ky*48 + kx*16 + ci  (so im2col can write 16-channel runs
// with ds_write_b128). Chunk (e,ks,nf,quad,lq) holds k' = ks*32+quad*8 .. +7 for
// n = nf*16+lq. k'==144 holds bias (pairs with A's 1.0 column), k'>144 zero.
__global__ __launch_bounds__(256) void prep_w_kernel(const float* __restrict__ ew,
                                                     const float* __restrict__ eb,
                                                     unsigned short* __restrict__ wb) {
    const int c = blockIdx.x * 256 + threadIdx.x;
    if (c >= 20480) return;                     // 16 e * 1280 chunks
    const int e    = c / 1280;
    const int r    = c - e * 1280;
    const int ks   = r >> 8;                    // 0..4
    const int nf   = (r >> 6) & 3;
    const int quad = (r >> 4) & 3;
    const int lq   = r & 15;
    const int n    = nf * 16 + lq;
    const int k0   = ks * 32 + quad * 8;        // aligned-8 block of k'
    uint4 dv = make_uint4(0u, 0u, 0u, 0u);
    if (k0 < 144) {
        // k' block never crosses a (ky,kx) boundary (16-sized ci runs, 8-aligned k0)
        const int ky  = k0 / 48;
        const int kx  = (k0 >> 4) % 3;
        const int ci0 = k0 & 15;                // 0 or 8
        // source k = ci*9 + ky*3 + kx  (OIHW [E][64][16][3][3])
        const float* s = ew + (e * 64 + n) * 144 + ci0 * 9 + ky * 3 + kx;
        float v[8];
        #pragma unroll
        for (int j = 0; j < 8; ++j) v[j] = s[j * 9];
        dv.x = f2bf(v[0]) | (f2bf(v[1]) << 16);
        dv.y = f2bf(v[2]) | (f2bf(v[3]) << 16);
        dv.z = f2bf(v[4]) | (f2bf(v[5]) << 16);
        dv.w = f2bf(v[6]) | (f2bf(v[7]) << 16);
    } else if (k0 == 144) {
        dv.x = f2bf(eb[e * 64 + n]);            // bias column
    }
    *(uint4*)(wb + c * 8) = dv;
}

// ---- main: M=64 dense GEMM; EXPERT-PAIRED e-loop (A reads shared 2x) ----
// grid: 2048 = b(8) x row(128) x half(2); block: 256 thr = 4 waves (wave = n-frag)
// REGISTER MODEL (measured r5/8/9/11/12/13): arch cap = 256/min_waves
// ((256,2)->128, (256,3)->84, (256,4)->64, (256,6)->40); live>cap => ~1GB scratch.
// ROUND-14 (cap 64, A-from-LDS per expert): 56-60us main, ZERO spill, and the
// LDS-port arithmetic matches: 1280 ds_read_b128/block x 12cyc x 8 blocks/CU =
// 51us. => LDS-port-throughput-bound.
// THIS ROUND (3rd resubmit; r15-r17 GPU timeouts): pair experts (e,e+1): both B
// sets resident (b0/b1 = 40 regs), each A ds_read feeds TWO MFMAs -> 640 reads/
// block, LDS floor ~26us. Live ~88-95 (b 40 + facc 16 + acc 8 + A 4 + wv 8 +
// addr ~12) -> cap 128 via (256,2), >=25 margin. (256,3)/cap-84 computes to ~86-90
// live = guaranteed spill; rejected. Port coverage at 8 waves/CU is the bet.
__global__ __launch_bounds__(256, 2) void moe_dense_kernel(
    const float* __restrict__ x,              // [8][16][128][128]
    const float* __restrict__ gw,             // [16][16]
    const float* __restrict__ gb,             // [16]
    const unsigned short* __restrict__ wb,    // [20480 chunks] bf16 (see prep)
    float* __restrict__ out,                  // [8][64][128][128]
    float* __restrict__ logits_out)           // [8][16][128][128]
{
    // 25,600 B union: [ Ab 21,504 B | wexp 4,096 B ]; outt (18,432 B) aliases Ab
    // after the post-e-loop barrier. wexp at 21,504 is outside outt -> never aliased.
    __shared__ __align__(16) unsigned char smem0[64 * 168 * 2 + 16 * 64 * 4];
    unsigned short* Ab   = (unsigned short*)smem0;            // [64][168] bf16
    float*          wexp = (float*)(smem0 + 64 * 168 * 2);    // [e][px] gate weight
    float*          outt = (float*)smem0;                     // [64][72] f32 (post-loop)

    const int tid = threadIdx.x;
    // T1 XCD swizzle (bijective: 2048 % 8 == 0): XCD i owns a contiguous bid range
    // -> adjacent rows/halves share halo rows + x panels in the same L2.
    const int bid = (blockIdx.x & 7) * 256 + (blockIdx.x >> 3);
    const int b   = bid >> 8;
    const int row = (bid >> 1) & 127;
    const int px0 = (bid & 1) << 6;

    const int lane = tid & 63;
    const int wave = tid >> 6;           // 0..3 = n-frag
    const int quad = lane >> 4;
    const int lq   = lane & 15;
    const int n    = lq + 16 * wave;     // this lane's cout

    const int px  = lane;
    const int col = px0 + px;

    // ---- phase 1 (single barrier at end): wave-specialized ----
    if (wave < 3) {
        // im2col for ky = wave; A row layout: k' = ky*48 + kx*16 + ci
        const int ky = wave;
        const int gr = row - 1 + ky;
        unsigned short* dst = Ab + px * 168 + ky * 48;
        if (gr < 0 || gr > 127) {        // wave-uniform branch (row 0 / row 127)
            const uint4 z = make_uint4(0u, 0u, 0u, 0u);
            *(uint4*)(dst)      = z; *(uint4*)(dst + 8)  = z;
            *(uint4*)(dst + 16) = z; *(uint4*)(dst + 24) = z;
            *(uint4*)(dst + 32) = z; *(uint4*)(dst + 40) = z;
        } else {
            float L[16], Mv[16], R[16];
            const float* xr = x + ((b * 16) * 128 + gr) * 128 + col;
            #pragma unroll
            for (int ci = 0; ci < 16; ++ci) {
                const float* p = xr + ci * 16384;
                Mv[ci] = p[0];
                L[ci]  = (col > 0)   ? p[-1] : 0.f;
                R[ci]  = (col < 127) ? p[1]  : 0.f;
            }
            pack16(dst,      L);         // kx = 0
            pack16(dst + 16, Mv);        // kx = 1
            pack16(dst + 32, R);         // kx = 2
        }
    } else {
        // gate logits + top-2 routing + logits_out + A k-pad, all in one wave
        // zero wexp first (this wave owns it pre-barrier; no ordering hazard)
        const float4 z4 = make_float4(0.f, 0.f, 0.f, 0.f);
        #pragma unroll
        for (int j = 0; j < 4; ++j)
            *(float4*)&wexp[(j * 64 + lane) * 4] = z4;
        float xv[16];
        const float* xp = x + (b * 16) * 16384 + row * 128 + col;
        #pragma unroll
        for (int ci = 0; ci < 16; ++ci) xv[ci] = xp[ci * 16384];
        float l[16];
        const int rbase = ((b * 16) * 128 + row) * 128 + col;
        #pragma unroll
        for (int o = 0; o < 16; ++o) {
            float acc = gb[o];
            #pragma unroll
            for (int i = 0; i < 16; ++i) acc += gw[o * 16 + i] * xv[i];
            l[o] = acc;
            logits_out[rbase + o * 16384] = acc;
        }
        float m = l[0];
        #pragma unroll
        for (int o = 1; o < 16; ++o) m = fmaxf(m, l[o]);
        float p0 = expf(l[0] - m), p1 = -1.f;
        int i0 = 0, i1 = 0;
        #pragma unroll
        for (int o = 1; o < 16; ++o) {
            float pv = expf(l[o] - m);
            if (pv > p0)      { p1 = p0; i1 = i0; p0 = pv; i0 = o; }
            else if (pv > p1) { p1 = pv; i1 = o; }
        }
        const float ws = p0 + p1;
        wexp[i0 * 64 + px] = p0 / ws;
        wexp[i1 * 64 + px] = p1 / ws;
        // A k-pad: k'144 = 1.0 (bias column), 145..167 = 0
        const uint4 z   = make_uint4(0u, 0u, 0u, 0u);
        const uint4 one = make_uint4(0x00003F80u, 0u, 0u, 0u);
        *(uint4*)(Ab + px * 168 + 144) = one;
        *(uint4*)(Ab + px * 168 + 152) = z;
        *(uint4*)(Ab + px * 168 + 160) = z;
    }
    __syncthreads();                     // Ab + wexp ready (persist through e-loop)

    // ---- phase 3: expert-paired e-loop; A from LDS shared across the pair ----
    const unsigned short* arow = Ab + lq * 168 + quad * 8;   // + mt*2688 per tile
    const unsigned short* bpe  = wb + wave * 512 + lane * 8; // advances 20480/pair
    f32x4 facc[4];
    #pragma unroll
    for (int mt = 0; mt < 4; ++mt) facc[mt] = (f32x4){0.f, 0.f, 0.f, 0.f};

    #pragma unroll 1
    for (int p = 0; p < 8; ++p) {
        const int e0 = 2 * p;
        bf16x8 b0[5], b1[5];
        #pragma unroll
        for (int ks = 0; ks < 5; ++ks) {
            b0[ks] = *(const bf16x8*)(bpe + ks * 2048);           // expert e0
            b1[ks] = *(const bf16x8*)(bpe + 10240 + ks * 2048);   // expert e0+1
        }
        __builtin_amdgcn_s_setprio(1);
        #pragma unroll
        for (int mt = 0; mt < 4; ++mt) {
            const unsigned short* ar = arow + mt * 2688;
            f32x4 acc0 = {0.f, 0.f, 0.f, 0.f};
            f32x4 acc1 = {0.f, 0.f, 0.f, 0.f};
            #pragma unroll
            for (int ks = 0; ks < 5; ++ks) {
                const bf16x8 a = *(const bf16x8*)(ar + ks * 32);   // ds_read_b128
                acc0 = __builtin_amdgcn_mfma_f32_16x16x32_bf16(a, b0[ks], acc0, 0, 0, 0);
                acc1 = __builtin_amdgcn_mfma_f32_16x16x32_bf16(a, b1[ks], acc1, 0, 0, 0);
            }
            const f32x4 wv0 = *(const f32x4*)&wexp[e0 * 64 + mt * 16 + quad * 4];
            const f32x4 wv1 = *(const f32x4*)&wexp[(e0 + 1) * 64 + mt * 16 + quad * 4];
            #pragma unroll
            for (int r = 0; r < 4; ++r)             // C/D: row(px)=quad*4+r, col(c)=lq
                facc[mt][r] += wv0[r] * acc0[r] + wv1[r] * acc1[r];
        }
        __builtin_amdgcn_s_setprio(0);
        bpe += 20480;
    }

    __syncthreads();                     // ALL waves done reading Ab/wexp -> outt may alias

    // ---- phase 4: transpose bounce in [c][px+pad] layout, all-b128 ----
    // facc[mt] holds px = mt*16+quad*4+{0..3} for cout n -> one ds_write_b128 each.
    // Stride 72 dwords: slot-group (2n+4mt+quad)%8 -> exactly 8 lanes/group =
    // wave64 b128 conflict-free minimum. Read side (2c+p4)%8 likewise.
    #pragma unroll
    for (int mt = 0; mt < 4; ++mt)
        *(f32x4*)&outt[n * 72 + mt * 16 + quad * 4] = facc[mt];
    __syncthreads();
    #pragma unroll
    for (int j = 0; j < 4; ++j) {
        const int idx = j * 256 + tid;          // 0..1023
        const int c   = idx >> 4;               // cout 0..63
        const int p4  = idx & 15;               // px/4 group 0..15
        const f32x4 v = *(const f32x4*)&outt[c * 72 + p4 * 4];    // ds_read_b128
        *(f32x4*)&out[((b * 64 + c) * 128 + row) * 128 + px0 + p4 * 4] = v;
    }
}

extern "C" void kernel_launch(void* const* d_in, const int* in_sizes, int n_in,
                              void* d_out, int out_size, void* d_ws, size_t ws_size,
                              hipStream_t stream) {
    const float* x  = (const float*)d_in[0];
    const float* gw = (const float*)d_in[1];
    const float* gb = (const float*)d_in[2];
    const float* ew = (const float*)d_in[3];
    const float* eb = (const float*)d_in[4];
    float* out        = (float*)d_out;
    float* logits_out = out + 8 * 64 * 128 * 128;
    unsigned short* wb = (unsigned short*)d_ws;      // 20480 chunks * 16 B = 327,680 B

    prep_w_kernel<<<dim3(80), dim3(256), 0, stream>>>(ew, eb, wb);
    moe_dense_kernel<<<dim3(2048), dim3(256), 0, stream>>>(
        x, gw, gb, wb, out, logits_out);
}

// Round 19
// 121.258 us; speedup vs baseline: 1.0032x; 1.0032x over previous
//
#include <hip/hip_runtime.h>
#include <cmath>

// B=8, Cin=16, H=W=128, Cout=64, E=16, K=2
typedef __attribute__((ext_vector_type(8))) short bf16x8;   // MFMA A/B frag
typedef __attribute__((ext_vector_type(4))) float f32x4;    // MFMA C/D frag

static __device__ __forceinline__ unsigned int f2bf(float f) {
    union { float f; unsigned int u; } v; v.f = f;
    unsigned int r = v.u + 0x7FFFu + ((v.u >> 16) & 1u);   // round-to-nearest-even
    return r >> 16;
}

// Pack 16 floats -> 16 bf16 -> two 16B LDS stores
static __device__ __forceinline__ void pack16(unsigned short* d, const float* v) {
    uint4 a, b2;
    a.x  = f2bf(v[0])  | (f2bf(v[1])  << 16);
    a.y  = f2bf(v[2])  | (f2bf(v[3])  << 16);
    a.z  = f2bf(v[4])  | (f2bf(v[5])  << 16);
    a.w  = f2bf(v[6])  | (f2bf(v[7])  << 16);
    b2.x = f2bf(v[8])  | (f2bf(v[9])  << 16);
    b2.y = f2bf(v[10]) | (f2bf(v[11]) << 16);
    b2.z = f2bf(v[12]) | (f2bf(v[13]) << 16);
    b2.w = f2bf(v[14]) | (f2bf(v[15]) << 16);
    *(uint4*)d       = a;
    *(uint4*)(d + 8) = b2;
}

// ---- prep: ew [16][64][144] fp32 + eb -> wb chunks [e][ks][nf][quad][lq] x 8 bf16 ----
// K-PERMUTED layout: k' = ky*48 + kx*16 + ci  (so im2col can write 16-channel runs
// with ds_write_b128). Chunk (e,ks,nf,quad,lq) holds k' = ks*32+quad*8 .. +7 for
// n = nf*16+lq. k'==144 holds bias (pairs with A's 1.0 column), k'>144 zero.
__global__ __launch_bounds__(256) void prep_w_kernel(const float* __restrict__ ew,
                                                     const float* __restrict__ eb,
                                                     unsigned short* __restrict__ wb) {
    const int c = blockIdx.x * 256 + threadIdx.x;
    if (c >= 20480) return;                     // 16 e * 1280 chunks
    const int e    = c / 1280;
    const int r    = c - e * 1280;
    const int ks   = r >> 8;                    // 0..4
    const int nf   = (r >> 6) & 3;
    const int quad = (r >> 4) & 3;
    const int lq   = r & 15;
    const int n    = nf * 16 + lq;
    const int k0   = ks * 32 + quad * 8;        // aligned-8 block of k'
    uint4 dv = make_uint4(0u, 0u, 0u, 0u);
    if (k0 < 144) {
        // k' block never crosses a (ky,kx) boundary (16-sized ci runs, 8-aligned k0)
        const int ky  = k0 / 48;
        const int kx  = (k0 >> 4) % 3;
        const int ci0 = k0 & 15;                // 0 or 8
        // source k = ci*9 + ky*3 + kx  (OIHW [E][64][16][3][3])
        const float* s = ew + (e * 64 + n) * 144 + ci0 * 9 + ky * 3 + kx;
        float v[8];
        #pragma unroll
        for (int j = 0; j < 8; ++j) v[j] = s[j * 9];
        dv.x = f2bf(v[0]) | (f2bf(v[1]) << 16);
        dv.y = f2bf(v[2]) | (f2bf(v[3]) << 16);
        dv.z = f2bf(v[4]) | (f2bf(v[5]) << 16);
        dv.w = f2bf(v[6]) | (f2bf(v[7]) << 16);
    } else if (k0 == 144) {
        dv.x = f2bf(eb[e * 64 + n]);            // bias column
    }
    *(uint4*)(wb + c * 8) = dv;
}

// ---- main: M=64 dense GEMM; EXPERT-PAIRED e-loop at 3 blocks/CU ----
// grid: 2048 = b(8) x row(128) x half(2); block: 256 thr = 4 waves (wave = n-frag)
// ROUND-18 MEASURED: paired body, VGPR=84 (compiler's natural choice), zero spill
// (FETCH 5.5MB/WRITE 41MB), 58us main -- identical to r14 despite HALVED LDS reads.
// => NOT LDS-port-bound. Component sum per CU (LDS 25us + B-L2 19us + MFMA 5us +
// phase1 ~6us + epi ~3us) == measured 58us: pipes run back-to-back, NO overlap.
// Concurrency-starved at 2 blocks/CU (occ 24%).
// THIS ROUND: ONE TOKEN -- launch_bounds (256,2)->(256,3). Cap 84 == the 84 the
// compiler already used freely, so no register change expected; residency rises
// to 3 blocks/CU = 12 waves -> LDS stream overlaps L2 stream overlaps MFMA pipe.
// Unified check: (84 arch + 84 AGPR-mirror) x 3 waves = 504 <= 512. OK.
__global__ __launch_bounds__(256, 3) void moe_dense_kernel(
    const float* __restrict__ x,              // [8][16][128][128]
    const float* __restrict__ gw,             // [16][16]
    const float* __restrict__ gb,             // [16]
    const unsigned short* __restrict__ wb,    // [20480 chunks] bf16 (see prep)
    float* __restrict__ out,                  // [8][64][128][128]
    float* __restrict__ logits_out)           // [8][16][128][128]
{
    // 25,600 B union: [ Ab 21,504 B | wexp 4,096 B ]; outt (18,432 B) aliases Ab
    // after the post-e-loop barrier. wexp at 21,504 is outside outt -> never aliased.
    __shared__ __align__(16) unsigned char smem0[64 * 168 * 2 + 16 * 64 * 4];
    unsigned short* Ab   = (unsigned short*)smem0;            // [64][168] bf16
    float*          wexp = (float*)(smem0 + 64 * 168 * 2);    // [e][px] gate weight
    float*          outt = (float*)smem0;                     // [64][72] f32 (post-loop)

    const int tid = threadIdx.x;
    // T1 XCD swizzle (bijective: 2048 % 8 == 0): XCD i owns a contiguous bid range
    // -> adjacent rows/halves share halo rows + x panels in the same L2.
    const int bid = (blockIdx.x & 7) * 256 + (blockIdx.x >> 3);
    const int b   = bid >> 8;
    const int row = (bid >> 1) & 127;
    const int px0 = (bid & 1) << 6;

    const int lane = tid & 63;
    const int wave = tid >> 6;           // 0..3 = n-frag
    const int quad = lane >> 4;
    const int lq   = lane & 15;
    const int n    = lq + 16 * wave;     // this lane's cout

    const int px  = lane;
    const int col = px0 + px;

    // ---- phase 1 (single barrier at end): wave-specialized ----
    if (wave < 3) {
        // im2col for ky = wave; A row layout: k' = ky*48 + kx*16 + ci
        const int ky = wave;
        const int gr = row - 1 + ky;
        unsigned short* dst = Ab + px * 168 + ky * 48;
        if (gr < 0 || gr > 127) {        // wave-uniform branch (row 0 / row 127)
            const uint4 z = make_uint4(0u, 0u, 0u, 0u);
            *(uint4*)(dst)      = z; *(uint4*)(dst + 8)  = z;
            *(uint4*)(dst + 16) = z; *(uint4*)(dst + 24) = z;
            *(uint4*)(dst + 32) = z; *(uint4*)(dst + 40) = z;
        } else {
            float L[16], Mv[16], R[16];
            const float* xr = x + ((b * 16) * 128 + gr) * 128 + col;
            #pragma unroll
            for (int ci = 0; ci < 16; ++ci) {
                const float* p = xr + ci * 16384;
                Mv[ci] = p[0];
                L[ci]  = (col > 0)   ? p[-1] : 0.f;
                R[ci]  = (col < 127) ? p[1]  : 0.f;
            }
            pack16(dst,      L);         // kx = 0
            pack16(dst + 16, Mv);        // kx = 1
            pack16(dst + 32, R);         // kx = 2
        }
    } else {
        // gate logits + top-2 routing + logits_out + A k-pad, all in one wave
        // zero wexp first (this wave owns it pre-barrier; no ordering hazard)
        const float4 z4 = make_float4(0.f, 0.f, 0.f, 0.f);
        #pragma unroll
        for (int j = 0; j < 4; ++j)
            *(float4*)&wexp[(j * 64 + lane) * 4] = z4;
        float xv[16];
        const float* xp = x + (b * 16) * 16384 + row * 128 + col;
        #pragma unroll
        for (int ci = 0; ci < 16; ++ci) xv[ci] = xp[ci * 16384];
        float l[16];
        const int rbase = ((b * 16) * 128 + row) * 128 + col;
        #pragma unroll
        for (int o = 0; o < 16; ++o) {
            float acc = gb[o];
            #pragma unroll
            for (int i = 0; i < 16; ++i) acc += gw[o * 16 + i] * xv[i];
            l[o] = acc;
            logits_out[rbase + o * 16384] = acc;
        }
        float m = l[0];
        #pragma unroll
        for (int o = 1; o < 16; ++o) m = fmaxf(m, l[o]);
        float p0 = expf(l[0] - m), p1 = -1.f;
        int i0 = 0, i1 = 0;
        #pragma unroll
        for (int o = 1; o < 16; ++o) {
            float pv = expf(l[o] - m);
            if (pv > p0)      { p1 = p0; i1 = i0; p0 = pv; i0 = o; }
            else if (pv > p1) { p1 = pv; i1 = o; }
        }
        const float ws = p0 + p1;
        wexp[i0 * 64 + px] = p0 / ws;
        wexp[i1 * 64 + px] = p1 / ws;
        // A k-pad: k'144 = 1.0 (bias column), 145..167 = 0
        const uint4 z   = make_uint4(0u, 0u, 0u, 0u);
        const uint4 one = make_uint4(0x00003F80u, 0u, 0u, 0u);
        *(uint4*)(Ab + px * 168 + 144) = one;
        *(uint4*)(Ab + px * 168 + 152) = z;
        *(uint4*)(Ab + px * 168 + 160) = z;
    }
    __syncthreads();                     // Ab + wexp ready (persist through e-loop)

    // ---- phase 3: expert-paired e-loop; A from LDS shared across the pair ----
    const unsigned short* arow = Ab + lq * 168 + quad * 8;   // + mt*2688 per tile
    const unsigned short* bpe  = wb + wave * 512 + lane * 8; // advances 20480/pair
    f32x4 facc[4];
    #pragma unroll
    for (int mt = 0; mt < 4; ++mt) facc[mt] = (f32x4){0.f, 0.f, 0.f, 0.f};

    #pragma unroll 1
    for (int p = 0; p < 8; ++p) {
        const int e0 = 2 * p;
        bf16x8 b0[5], b1[5];
        #pragma unroll
        for (int ks = 0; ks < 5; ++ks) {
            b0[ks] = *(const bf16x8*)(bpe + ks * 2048);           // expert e0
            b1[ks] = *(const bf16x8*)(bpe + 10240 + ks * 2048);   // expert e0+1
        }
        __builtin_amdgcn_s_setprio(1);
        #pragma unroll
        for (int mt = 0; mt < 4; ++mt) {
            const unsigned short* ar = arow + mt * 2688;
            f32x4 acc0 = {0.f, 0.f, 0.f, 0.f};
            f32x4 acc1 = {0.f, 0.f, 0.f, 0.f};
            #pragma unroll
            for (int ks = 0; ks < 5; ++ks) {
                const bf16x8 a = *(const bf16x8*)(ar + ks * 32);   // ds_read_b128
                acc0 = __builtin_amdgcn_mfma_f32_16x16x32_bf16(a, b0[ks], acc0, 0, 0, 0);
                acc1 = __builtin_amdgcn_mfma_f32_16x16x32_bf16(a, b1[ks], acc1, 0, 0, 0);
            }
            const f32x4 wv0 = *(const f32x4*)&wexp[e0 * 64 + mt * 16 + quad * 4];
            const f32x4 wv1 = *(const f32x4*)&wexp[(e0 + 1) * 64 + mt * 16 + quad * 4];
            #pragma unroll
            for (int r = 0; r < 4; ++r)             // C/D: row(px)=quad*4+r, col(c)=lq
                facc[mt][r] += wv0[r] * acc0[r] + wv1[r] * acc1[r];
        }
        __builtin_amdgcn_s_setprio(0);
        bpe += 20480;
    }

    __syncthreads();                     // ALL waves done reading Ab/wexp -> outt may alias

    // ---- phase 4: transpose bounce in [c][px+pad] layout, all-b128 ----
    // facc[mt] holds px = mt*16+quad*4+{0..3} for cout n -> one ds_write_b128 each.
    // Stride 72 dwords: slot-group (2n+4mt+quad)%8 -> exactly 8 lanes/group =
    // wave64 b128 conflict-free minimum. Read side (2c+p4)%8 likewise.
    #pragma unroll
    for (int mt = 0; mt < 4; ++mt)
        *(f32x4*)&outt[n * 72 + mt * 16 + quad * 4] = facc[mt];
    __syncthreads();
    #pragma unroll
    for (int j = 0; j < 4; ++j) {
        const int idx = j * 256 + tid;          // 0..1023
        const int c   = idx >> 4;               // cout 0..63
        const int p4  = idx & 15;               // px/4 group 0..15
        const f32x4 v = *(const f32x4*)&outt[c * 72 + p4 * 4];    // ds_read_b128
        *(f32x4*)&out[((b * 64 + c) * 128 + row) * 128 + px0 + p4 * 4] = v;
    }
}

extern "C" void kernel_launch(void* const* d_in, const int* in_sizes, int n_in,
                              void* d_out, int out_size, void* d_ws, size_t ws_size,
                              hipStream_t stream) {
    const float* x  = (const float*)d_in[0];
    const float* gw = (const float*)d_in[1];
    const float* gb = (const float*)d_in[2];
    const float* ew = (const float*)d_in[3];
    const float* eb = (const float*)d_in[4];
    float* out        = (float*)d_out;
    float* logits_out = out + 8 * 64 * 128 * 128;
    unsigned short* wb = (unsigned short*)d_ws;      // 20480 chunks * 16 B = 327,680 B

    prep_w_kernel<<<dim3(80), dim3(256), 0, stream>>>(ew, eb, wb);
    moe_dense_kernel<<<dim3(2048), dim3(256), 0, stream>>>(
        x, gw, gb, wb, out, logits_out);
}